// Round 5
// baseline (9333.978 us; speedup 1.0000x reference)
//
#include <hip/hip_runtime.h>
#include <hip/hip_bf16.h>
#include <stdint.h>

#define DEV __device__ __forceinline__
typedef unsigned short u16;
typedef unsigned int   u32;

static constexpr int SS = 256;   // src len
static constexpr int TT = 64;    // tgt len
static constexpr int EE = 256;   // embed dim
static constexpr int HH = 512;   // hidden
static constexpr int G3 = 1536;  // 3*H
static constexpr int VV = 32000; // vocab
static constexpr int HP = 516;   // padded LDS row (516%32==4 -> 4-way max)

// ---------- helpers ----------
DEV float blo(u32 u){ union{u32 i; float f;} x; x.i = u << 16;         return x.f; }
DEV float bhi(u32 u){ union{u32 i; float f;} x; x.i = u & 0xffff0000u; return x.f; }
DEV float bf2f(u16 u){ union{u32 i; float f;} x; x.i = ((u32)u) << 16; return x.f; }
DEV u16 f2bf(float f){ union{float f; u32 u;} v; v.f = f;
  u32 r = v.u + 0x7fffu + ((v.u >> 16) & 1u); return (u16)(r >> 16); }
DEV float sigf (float x){ return 1.0f / (1.0f + __expf(-x)); }
DEV float tanh_(float x){ return 1.0f - 2.0f / (1.0f + __expf(2.0f * x)); }

DEV void unp8(float* d, uint4 u){   // 8 bf16 (internal buffers) -> f32
  d[0]=blo(u.x); d[1]=bhi(u.x); d[2]=blo(u.y); d[3]=bhi(u.y);
  d[4]=blo(u.z); d[5]=bhi(u.z); d[6]=blo(u.w); d[7]=bhi(u.w);
}
DEV float dot4(float acc, float4 w, float4 x){
  acc = fmaf(w.x,x.x,acc); acc = fmaf(w.y,x.y,acc);
  acc = fmaf(w.z,x.z,acc); acc = fmaf(w.w,x.w,acc);
  return acc;
}
DEV float fma44(float acc, float4 w0, float4 w1, float4 h0, float4 h1){
  return dot4(dot4(acc, w0, h0), w1, h1);
}

// ---------- K1: gi = gather(emb, tok) @ W[:, :256]^T + bih  (bf16 out) ----
// rows r = t*32 + b; f32 inputs, bf16 internal output.
__global__ __launch_bounds__(256)
void k_embed_gemm(const int* __restrict__ tok, int Tlen,
                  const float* __restrict__ emb,
                  const float* __restrict__ W, int wstride,
                  const float* __restrict__ bias,
                  u16* __restrict__ gi)
{
  __shared__ float es[16][EE];
  const int tid = threadIdx.x;
  const int r0 = blockIdx.y * 16;
  #pragma unroll
  for (int rr = 0; rr < 16; ++rr) {
    int r = r0 + rr;
    int token = tok[(r & 31) * Tlen + (r >> 5)];
    es[rr][tid] = emb[(size_t)token * EE + tid];
  }
  __syncthreads();
  const int jl = tid & 63;
  const int rg = (tid >> 6) << 2;
  const int jbase = blockIdx.x * 256 + jl;
  float acc[4][4];
  #pragma unroll
  for (int jj = 0; jj < 4; ++jj) {
    float bv = bias[jbase + jj * 64];
    #pragma unroll
    for (int rr = 0; rr < 4; ++rr) acc[jj][rr] = bv;
  }
  const float4* w0 = (const float4*)(W + (size_t)(jbase      ) * wstride);
  const float4* w1 = (const float4*)(W + (size_t)(jbase +  64) * wstride);
  const float4* w2 = (const float4*)(W + (size_t)(jbase + 128) * wstride);
  const float4* w3 = (const float4*)(W + (size_t)(jbase + 192) * wstride);
  for (int k4 = 0; k4 < EE / 4; ++k4) {
    float4 wv0 = w0[k4], wv1 = w1[k4], wv2 = w2[k4], wv3 = w3[k4];
    #pragma unroll
    for (int rr = 0; rr < 4; ++rr) {
      float4 e = *(const float4*)&es[rg + rr][k4 * 4];
      acc[0][rr] = dot4(acc[0][rr], wv0, e);
      acc[1][rr] = dot4(acc[1][rr], wv1, e);
      acc[2][rr] = dot4(acc[2][rr], wv2, e);
      acc[3][rr] = dot4(acc[3][rr], wv3, e);
    }
  }
  #pragma unroll
  for (int rr = 0; rr < 4; ++rr)
    #pragma unroll
    for (int jj = 0; jj < 4; ++jj)
      gi[(size_t)(r0 + rg + rr) * G3 + jbase + jj * 64] = f2bf(acc[jj][rr]);
}

// ---------- K2: one encoder GRU step (launched 256x) ----------
// grid 128 blocks: block owns 4 output i's (all 3 gates), all 32 b.
__global__ __launch_bounds__(256)
void k_enc_step(const u16* __restrict__ gi, const float* __restrict__ Whh,
                const float* __restrict__ bhh, const u16* __restrict__ hin,
                u16* __restrict__ hout, u16* __restrict__ enc_outs, int t)
{
  __shared__ float hs[32 * HP];        // 66.0 KB
  __shared__ float wsl[3 * 4 * 512];   // 24.0 KB
  const int tid = threadIdx.x;
  const int i0 = blockIdx.x * 4;
  #pragma unroll
  for (int j = 0; j < 8; ++j) {        // stage h: 16384 bf16 -> f32 (exact)
    int f0 = (j * 256 + tid) * 8;
    int b = f0 >> 9, k = f0 & 511;
    float d[8]; unp8(d, *(const uint4*)(hin + f0));
    *(float4*)&hs[b * HP + k]     = make_float4(d[0],d[1],d[2],d[3]);
    *(float4*)&hs[b * HP + k + 4] = make_float4(d[4],d[5],d[6],d[7]);
  }
  // stage weights: 12 rows x 512 f32 = 6144 floats = 6 * 256thr * float4
  #pragma unroll
  for (int j = 0; j < 6; ++j) {
    int f = (j * 256 + tid) * 4;
    int g = f >> 11, r = f & 2047;
    int row = g * 512 + i0 + (r >> 9), k = r & 511;
    *(float4*)&wsl[f] = *(const float4*)(Whh + (size_t)row * 512 + k);
  }
  __syncthreads();
  const int i_l = tid >> 6, lane = tid & 63, b = lane >> 1, kh = lane & 1;
  const int i = i0 + i_l;
  float aR = 0.f, aZ = 0.f, aN = 0.f;
  const float* hb = hs  + b * HP + kh * 256;
  const float* w0 = wsl + (0 * 4 + i_l) * 512 + kh * 256;
  const float* w1 = wsl + (1 * 4 + i_l) * 512 + kh * 256;
  const float* w2 = wsl + (2 * 4 + i_l) * 512 + kh * 256;
  for (int k8 = 0; k8 < 32; ++k8) {
    float4 h0 = *(const float4*)&hb[k8*8], h1 = *(const float4*)&hb[k8*8+4];
    aR = fma44(aR, *(const float4*)&w0[k8*8], *(const float4*)&w0[k8*8+4], h0, h1);
    aZ = fma44(aZ, *(const float4*)&w1[k8*8], *(const float4*)&w1[k8*8+4], h0, h1);
    aN = fma44(aN, *(const float4*)&w2[k8*8], *(const float4*)&w2[k8*8+4], h0, h1);
  }
  aR += __shfl_xor(aR, 1);
  aZ += __shfl_xor(aZ, 1);
  aN += __shfl_xor(aN, 1);
  if (kh == 0) {
    const size_t g = ((size_t)t * 32 + b) * G3;
    float r = sigf (bf2f(gi[g +        i]) + aR + bhh[i]);
    float z = sigf (bf2f(gi[g +  512 + i]) + aZ + bhh[i + 512]);
    float n = tanh_(bf2f(gi[g + 1024 + i]) + r * (aN + bhh[i + 1024]));
    float h2 = z * hs[b * HP + i] + (1.f - z) * n;
    u16 hb16 = f2bf(h2);
    hout[b * 512 + i] = hb16;
    enc_outs[((size_t)b * 256 + t) * 512 + i] = hb16;
  }
}

// ---------- K3: enc_proj = enc_outs @ attn_W2^T + b2 ----------
// A: bf16 internal; W,bias: f32 inputs; Out: bf16 internal.
__global__ __launch_bounds__(256)
void k_proj(const u16* __restrict__ A, const float* __restrict__ W,
            const float* __restrict__ bias, u16* __restrict__ Out)
{
  __shared__ float es[16][HH];
  const int tid = threadIdx.x;
  const int r0 = blockIdx.y * 16;
  #pragma unroll
  for (int j = 0; j < 4; ++j) {
    int u = j * 256 + tid;             // 1024 uint4 slots = 16 rows x 64
    int row = u >> 6, k = (u & 63) * 8;
    float d[8]; unp8(d, *(const uint4*)(A + (size_t)(r0 + row) * HH + k));
    *(float4*)&es[row][k]     = make_float4(d[0],d[1],d[2],d[3]);
    *(float4*)&es[row][k + 4] = make_float4(d[4],d[5],d[6],d[7]);
  }
  __syncthreads();
  const int jl = tid & 63;
  const int rg = (tid >> 6) << 2;
  const int jbase = blockIdx.x * 256 + jl;
  float acc[4][4];
  #pragma unroll
  for (int jj = 0; jj < 4; ++jj) {
    float bv = bias[jbase + jj * 64];
    #pragma unroll
    for (int rr = 0; rr < 4; ++rr) acc[jj][rr] = bv;
  }
  const float4* w0 = (const float4*)(W + (size_t)(jbase      ) * HH);
  const float4* w1 = (const float4*)(W + (size_t)(jbase +  64) * HH);
  const float4* w2 = (const float4*)(W + (size_t)(jbase + 128) * HH);
  const float4* w3 = (const float4*)(W + (size_t)(jbase + 192) * HH);
  for (int k4 = 0; k4 < HH / 4; ++k4) {
    float4 wv0 = w0[k4], wv1 = w1[k4], wv2 = w2[k4], wv3 = w3[k4];
    #pragma unroll
    for (int rr = 0; rr < 4; ++rr) {
      float4 e = *(const float4*)&es[rg + rr][k4 * 4];
      acc[0][rr] = dot4(acc[0][rr], wv0, e);
      acc[1][rr] = dot4(acc[1][rr], wv1, e);
      acc[2][rr] = dot4(acc[2][rr], wv2, e);
      acc[3][rr] = dot4(acc[3][rr], wv3, e);
    }
  }
  #pragma unroll
  for (int rr = 0; rr < 4; ++rr)
    #pragma unroll
    for (int jj = 0; jj < 4; ++jj)
      Out[(size_t)(r0 + rg + rr) * HH + jbase + jj * 64] = f2bf(acc[jj][rr]);
}

// ---------- K4: a = h @ W1^T + b1 (per decoder step) ----------
__global__ __launch_bounds__(256)
void k_dec_a(const u16* __restrict__ hin, const float* __restrict__ W1,
             const float* __restrict__ b1, float* __restrict__ a_buf)
{
  __shared__ float hs[32 * HP];
  const int tid = threadIdx.x;
  const int i0 = blockIdx.x * 8;
  #pragma unroll
  for (int j = 0; j < 8; ++j) {
    int f0 = (j * 256 + tid) * 8;
    int b = f0 >> 9, k = f0 & 511;
    float d[8]; unp8(d, *(const uint4*)(hin + f0));
    *(float4*)&hs[b * HP + k]     = make_float4(d[0],d[1],d[2],d[3]);
    *(float4*)&hs[b * HP + k + 4] = make_float4(d[4],d[5],d[6],d[7]);
  }
  __syncthreads();
  const int i_l = tid >> 5, b = tid & 31, i = i0 + i_l;
  const float4* w = (const float4*)(W1 + (size_t)i * 512);
  const float* hb = hs + b * HP;
  float acc = b1[i];
  for (int k4 = 0; k4 < 128; ++k4)
    acc = dot4(acc, w[k4], *(const float4*)&hb[k4 * 4]);
  a_buf[b * 512 + i] = acc;
}

// ---------- K5: attention scores + partial softmax + partial ctx ----------
// grid 128 = (b, s-quarter). Unnormalized flash-style partials.
__global__ __launch_bounds__(256)
void k_dec_attn(const float* __restrict__ a_buf, const u16* __restrict__ enc_proj,
                const u16* __restrict__ enc_outs, const float* __restrict__ av,
                u16* __restrict__ ctxp, float* __restrict__ mS)
{
  __shared__ float as_[512], vs_[512], scq[4][64], wts[64];
  const int tid = threadIdx.x;
  const int b = blockIdx.x >> 2, sq = blockIdx.x & 3;
  as_[tid] = a_buf[b * 512 + tid]; as_[tid + 256] = a_buf[b * 512 + tid + 256];
  vs_[tid] = av[tid];              vs_[tid + 256] = av[tid + 256];
  __syncthreads();
  {
    const int kp = tid >> 6, s_l = tid & 63;
    const int s = sq * 64 + s_l;
    const u16* pr = enc_proj + ((size_t)b * 256 + s) * 512 + kp * 128;
    const float* ak = as_ + kp * 128;
    const float* vk = vs_ + kp * 128;
    float acc = 0.f;
    for (int k8 = 0; k8 < 16; ++k8) {
      float d[8]; unp8(d, *(const uint4*)(pr + k8 * 8));
      #pragma unroll
      for (int e = 0; e < 8; ++e)
        acc += vk[k8 * 8 + e] * tanh_(d[e] + ak[k8 * 8 + e]);
    }
    scq[kp][s_l] = acc;
  }
  __syncthreads();
  if (tid < 64) {
    float sc = (scq[0][tid] + scq[1][tid]) + (scq[2][tid] + scq[3][tid]);
    float m = sc;
    #pragma unroll
    for (int d = 1; d < 64; d <<= 1) m = fmaxf(m, __shfl_xor(m, d));
    float e = __expf(sc - m);
    float su = e;
    #pragma unroll
    for (int d = 1; d < 64; d <<= 1) su += __shfl_xor(su, d);
    wts[tid] = e;
    if (tid == 0) { mS[(sq * 32 + b) * 2] = m; mS[(sq * 32 + b) * 2 + 1] = su; }
  }
  __syncthreads();
  {
    const int k0 = tid * 2;
    float c0 = 0.f, c1 = 0.f;
    const u16* eo = enc_outs + ((size_t)b * 256 + sq * 64) * 512 + k0;
    for (int s = 0; s < 64; ++s) {
      float w = wts[s];
      u32 pair = *(const u32*)(eo + (size_t)s * 512);
      c0 = fmaf(w, blo(pair), c0);
      c1 = fmaf(w, bhi(pair), c1);
    }
    ctxp[((size_t)sq * 32 + b) * 512 + k0    ] = f2bf(c0);
    ctxp[((size_t)sq * 32 + b) * 512 + k0 + 1] = f2bf(c1);
  }
}

// ---------- K6: decoder GRU step ----------
__global__ __launch_bounds__(256)
void k_dec_gru(const u16* __restrict__ gi, const u16* __restrict__ hin,
               const u16* __restrict__ ctxp, const float* __restrict__ mS,
               const float* __restrict__ Whh, const float* __restrict__ Wih,
               const float* __restrict__ bhh, u16* __restrict__ hout,
               float* __restrict__ h2_all, int t)
{
  __shared__ float hs[32 * HP];
  __shared__ float cs[32 * HP];
  __shared__ float alp[32][4];
  const int tid = threadIdx.x;
  const int i0 = blockIdx.x * 4;
  if (tid < 32) {
    float m0 = mS[(0*32+tid)*2], s0 = mS[(0*32+tid)*2+1];
    float m1 = mS[(1*32+tid)*2], s1 = mS[(1*32+tid)*2+1];
    float m2 = mS[(2*32+tid)*2], s2 = mS[(2*32+tid)*2+1];
    float m3 = mS[(3*32+tid)*2], s3 = mS[(3*32+tid)*2+1];
    float M = fmaxf(fmaxf(m0, m1), fmaxf(m2, m3));
    float e0 = __expf(m0 - M), e1 = __expf(m1 - M);
    float e2 = __expf(m2 - M), e3 = __expf(m3 - M);
    float rd = 1.f / (s0*e0 + s1*e1 + s2*e2 + s3*e3);
    alp[tid][0] = e0*rd; alp[tid][1] = e1*rd; alp[tid][2] = e2*rd; alp[tid][3] = e3*rd;
  }
  __syncthreads();
  #pragma unroll
  for (int j = 0; j < 8; ++j) {
    int f0 = (j * 256 + tid) * 8;
    int b = f0 >> 9, k = f0 & 511;
    float d[8]; unp8(d, *(const uint4*)(hin + f0));
    *(float4*)&hs[b * HP + k]     = make_float4(d[0],d[1],d[2],d[3]);
    *(float4*)&hs[b * HP + k + 4] = make_float4(d[4],d[5],d[6],d[7]);
    float ce[8] = {0,0,0,0,0,0,0,0};
    #pragma unroll
    for (int q = 0; q < 4; ++q) {
      float aq = alp[b][q];
      float cd[8]; unp8(cd, *(const uint4*)(ctxp + ((size_t)q * 32 + b) * 512 + k));
      #pragma unroll
      for (int e = 0; e < 8; ++e) ce[e] = fmaf(aq, cd[e], ce[e]);
    }
    *(float4*)&cs[b * HP + k]     = make_float4(ce[0],ce[1],ce[2],ce[3]);
    *(float4*)&cs[b * HP + k + 4] = make_float4(ce[4],ce[5],ce[6],ce[7]);
  }
  __syncthreads();
  const int i_l = tid >> 6, lane = tid & 63, b = lane >> 1, kh = lane & 1;
  const int i = i0 + i_l;
  const float4* whr = (const float4*)(Whh + (size_t)(i       ) * 512 + kh * 256);
  const float4* whz = (const float4*)(Whh + (size_t)(i +  512) * 512 + kh * 256);
  const float4* whn = (const float4*)(Whh + (size_t)(i + 1024) * 512 + kh * 256);
  const float4* wir = (const float4*)(Wih + (size_t)(i       ) * 768 + 256 + kh * 256);
  const float4* wiz = (const float4*)(Wih + (size_t)(i +  512) * 768 + 256 + kh * 256);
  const float4* win = (const float4*)(Wih + (size_t)(i + 1024) * 768 + 256 + kh * 256);
  const float* hb = hs + b * HP + kh * 256;
  const float* cb = cs + b * HP + kh * 256;
  float hR=0.f,hZ=0.f,hN=0.f,cR=0.f,cZ=0.f,cN=0.f;
  for (int k4 = 0; k4 < 64; ++k4) {
    float4 h = *(const float4*)&hb[k4*4];
    float4 c = *(const float4*)&cb[k4*4];
    hR = dot4(hR, whr[k4], h);
    hZ = dot4(hZ, whz[k4], h);
    hN = dot4(hN, whn[k4], h);
    cR = dot4(cR, wir[k4], c);
    cZ = dot4(cZ, wiz[k4], c);
    cN = dot4(cN, win[k4], c);
  }
  hR += __shfl_xor(hR, 1); hZ += __shfl_xor(hZ, 1); hN += __shfl_xor(hN, 1);
  cR += __shfl_xor(cR, 1); cZ += __shfl_xor(cZ, 1); cN += __shfl_xor(cN, 1);
  if (kh == 0) {
    const size_t g = ((size_t)t * 32 + b) * G3;
    float r = sigf (bf2f(gi[g +        i]) + cR + hR + bhh[i]);
    float z = sigf (bf2f(gi[g +  512 + i]) + cZ + hZ + bhh[i + 512]);
    float n = tanh_(bf2f(gi[g + 1024 + i]) + cN + r * (hN + bhh[i + 1024]));
    float h2 = z * hs[b * HP + i] + (1.f - z) * n;
    hout[b * 512 + i] = f2bf(h2);
    h2_all[((size_t)t * 32 + b) * 512 + i] = h2;
  }
}

// ---------- K7: logits = h2_all @ fc_W^T + fc_b -> out[b][t][v] (f32) ----
__global__ __launch_bounds__(256)
void k_logits(const float* __restrict__ A, const float* __restrict__ W,
              const float* __restrict__ bias, float* __restrict__ out)
{
  __shared__ float As[64][68];
  const int tid = threadIdx.x;
  const int vt = tid & 15;
  const int rt = tid >> 4;
  const int r0 = blockIdx.x * 64;
  const int v0 = blockIdx.y * 64;
  float acc[4][4];
  #pragma unroll
  for (int vv = 0; vv < 4; ++vv) {
    float bv = bias[v0 + vt + vv * 16];
    #pragma unroll
    for (int rr = 0; rr < 4; ++rr) acc[vv][rr] = bv;
  }
  const float4* wp0 = (const float4*)(W + (size_t)(v0 + vt     ) * HH);
  const float4* wp1 = (const float4*)(W + (size_t)(v0 + vt + 16) * HH);
  const float4* wp2 = (const float4*)(W + (size_t)(v0 + vt + 32) * HH);
  const float4* wp3 = (const float4*)(W + (size_t)(v0 + vt + 48) * HH);
  for (int kc = 0; kc < 8; ++kc) {
    __syncthreads();
    #pragma unroll
    for (int m = 0; m < 16; ++m) {
      int idx = m * 256 + tid;
      As[idx >> 6][idx & 63] = A[(size_t)(r0 + (idx >> 6)) * HH + kc * 64 + (idx & 63)];
    }
    __syncthreads();
    for (int k4 = 0; k4 < 16; ++k4) {
      float4 wv0 = wp0[kc * 16 + k4];
      float4 wv1 = wp1[kc * 16 + k4];
      float4 wv2 = wp2[kc * 16 + k4];
      float4 wv3 = wp3[kc * 16 + k4];
      #pragma unroll
      for (int rr = 0; rr < 4; ++rr) {
        float4 a = *(const float4*)&As[rt + rr * 16][k4 * 4];
        acc[0][rr] = dot4(acc[0][rr], wv0, a);
        acc[1][rr] = dot4(acc[1][rr], wv1, a);
        acc[2][rr] = dot4(acc[2][rr], wv2, a);
        acc[3][rr] = dot4(acc[3][rr], wv3, a);
      }
    }
  }
  #pragma unroll
  for (int rr = 0; rr < 4; ++rr) {
    const int r = r0 + rt + rr * 16;          // r = t*32+b
    const size_t ob = ((size_t)(r & 31) * 64 + (r >> 5)) * VV + v0 + vt;
    #pragma unroll
    for (int vv = 0; vv < 4; ++vv)
      out[ob + vv * 16] = acc[vv][rr];
  }
}

// ---------- launch ----------
extern "C" void kernel_launch(void* const* d_in, const int* in_sizes, int n_in,
                              void* d_out, int out_size, void* d_ws, size_t ws_size,
                              hipStream_t stream) {
  (void)in_sizes; (void)n_in; (void)out_size; (void)ws_size;
  const int*   src  = (const int*)d_in[0];
  const int*   tgt  = (const int*)d_in[1];
  const float* eemb = (const float*)d_in[2];
  const float* eWih = (const float*)d_in[3];
  const float* eWhh = (const float*)d_in[4];
  const float* ebih = (const float*)d_in[5];
  const float* ebhh = (const float*)d_in[6];
  const float* demb = (const float*)d_in[7];
  const float* aW1  = (const float*)d_in[8];
  const float* ab1  = (const float*)d_in[9];
  const float* aW2  = (const float*)d_in[10];
  const float* ab2  = (const float*)d_in[11];
  const float* av   = (const float*)d_in[12];
  const float* dWih = (const float*)d_in[13];
  const float* dWhh = (const float*)d_in[14];
  const float* dbih = (const float*)d_in[15];
  const float* dbhh = (const float*)d_in[16];
  const float* fcW  = (const float*)d_in[17];
  const float* fcb  = (const float*)d_in[18];
  float* out = (float*)d_out;

  // workspace carve (~53 MiB total); internal activations bf16, h2_all f32
  float* h2_all  = (float*)d_ws;                 // 1,048,576 f32
  float* a_buf   = h2_all + 1048576;             //    16,384 f32
  float* mS      = a_buf  + 16384;               //       256 f32
  u16*  ctxp     = (u16*)(mS + 256);             //    65,536 u16
  u16*  hbufE    = ctxp + 65536;                 //    32,768 u16 (2 x 32 x 512)
  u16*  gi_enc   = hbufE + 32768;                // 12,582,912 u16 (8192 x 1536)
  u16*  gi_dec   = gi_enc + 12582912;            //  3,145,728 u16 (2048 x 1536)
  u16*  enc_outs = gi_dec + 3145728;             //  4,194,304 u16 (32*256*512)
  u16*  enc_proj = enc_outs + 4194304;           //  4,194,304 u16 (32*256*512)
  // ^^^ round-4 bug: offset was 2097152 -> enc_proj overlapped enc_outs b>=16

  hipMemsetAsync(hbufE, 0, 32768 * sizeof(u16), stream);   // h0 = 0 (both bufs)

  k_embed_gemm<<<dim3(6, 512), 256, 0, stream>>>(src, SS, eemb, eWih, EE,  ebih, gi_enc);
  k_embed_gemm<<<dim3(6, 128), 256, 0, stream>>>(tgt, TT, demb, dWih, 768, dbih, gi_dec);

  for (int t = 0; t < SS; ++t) {
    u16* hin  = hbufE + (t & 1) * 16384;
    u16* hout = hbufE + ((t + 1) & 1) * 16384;
    k_enc_step<<<128, 256, 0, stream>>>(gi_enc, eWhh, ebhh, hin, hout, enc_outs, t);
  }

  k_proj<<<dim3(2, 512), 256, 0, stream>>>(enc_outs, aW2, ab2, enc_proj);

  for (int t = 0; t < TT; ++t) {
    u16* hin  = hbufE + (t & 1) * 16384;
    u16* hout = hbufE + ((t + 1) & 1) * 16384;
    k_dec_a   <<< 64, 256, 0, stream>>>(hin, aW1, ab1, a_buf);
    k_dec_attn<<<128, 256, 0, stream>>>(a_buf, enc_proj, enc_outs, av, ctxp, mS);
    k_dec_gru <<<128, 256, 0, stream>>>(gi_dec, hin, ctxp, mS, dWhh, dWih, dbhh,
                                        hout, h2_all, t);
  }

  k_logits<<<dim3(32, 500), 256, 0, stream>>>(h2_all, fcW, fcb, out);
}